// Round 3
// baseline (542.901 us; speedup 1.0000x reference)
//
#include <hip/hip_runtime.h>

#define BB 2
#define LL 512
#define HH 128
#define NH 8
#define SP_STRIDE 9   // pad 8 heads to 9 -> odd stride, conflict-free

typedef float f32x4 __attribute__((ext_vector_type(4)));

// K1: q = x@Wq+bq ; kp = x@Wk+bk+abs_pos_k ; vp = x@Wv+bv+abs_pos_v
__global__ __launch_bounds__(128) void qkv_proj_kernel(
    const float* __restrict__ x,
    const float* __restrict__ abs_pos_k,
    const float* __restrict__ abs_pos_v,
    const float* __restrict__ Wq, const float* __restrict__ bq,
    const float* __restrict__ Wk, const float* __restrict__ bk,
    const float* __restrict__ Wv, const float* __restrict__ bv,
    float* __restrict__ q, float* __restrict__ kp, float* __restrict__ vp)
{
    const int r0 = blockIdx.x * 4;
    const int c = threadIdx.x;
    __shared__ float xs[4][HH];
    #pragma unroll
    for (int r = 0; r < 4; ++r) xs[r][c] = x[(r0 + r) * HH + c];
    __syncthreads();
    float aq[4], ak[4], av[4];
    #pragma unroll
    for (int r = 0; r < 4; ++r) { aq[r] = bq[c]; ak[r] = bk[c]; av[r] = bv[c]; }
    #pragma unroll 4
    for (int i = 0; i < HH; ++i) {
        const float wq = Wq[i * HH + c];
        const float wk = Wk[i * HH + c];
        const float wv = Wv[i * HH + c];
        #pragma unroll
        for (int r = 0; r < 4; ++r) {
            const float xv = xs[r][i];
            aq[r] = fmaf(xv, wq, aq[r]);
            ak[r] = fmaf(xv, wk, ak[r]);
            av[r] = fmaf(xv, wv, av[r]);
        }
    }
    #pragma unroll
    for (int r = 0; r < 4; ++r) {
        const int idx = (r0 + r) * HH + c;
        q[idx]  = aq[r];
        kp[idx] = ak[r] + abs_pos_k[idx];
        vp[idx] = av[r] + abs_pos_v[idx];
    }
}

// K_A: raw scores for one ki-half of one (b,qi) row.
//   grid = BB*LL*2, 256 threads. t = kis*32 + c4, h = c4>>2.
//   scores layout: [row][ki 0..511][h 0..7]  (row = b*LL+qi)
__global__ __launch_bounds__(256) void score_kernel(
    const float* __restrict__ q,
    const float* __restrict__ kp,
    const float* __restrict__ time_k,
    float* __restrict__ scores)
{
    const int half = blockIdx.x & 1;
    const int row  = blockIdx.x >> 1;
    const int b    = row >> 9;
    const int t    = threadIdx.x;
    const int c4   = t & 31;
    const int kis  = t >> 5;
    const int h    = c4 >> 2;

    __shared__ float s_q[HH];
    __shared__ float s_p[(LL / 2) * SP_STRIDE];   // 256 ki x 8 h, pad 9

    if (t < HH) s_q[t] = q[row * HH + t];
    __syncthreads();

    const float4 q4 = ((const float4*)s_q)[c4];
    const f32x4*  __restrict__ tk4 = (const f32x4*)(time_k
        + (size_t)row * (size_t)(LL * HH) + (size_t)half * (LL / 2) * HH);
    const float4* __restrict__ kq4 = (const float4*)(kp
        + (size_t)b * (size_t)(LL * HH) + (size_t)half * (LL / 2) * HH);

    #pragma unroll 8
    for (int kb = 0; kb < LL / 2 / 8; ++kb) {
        const int ki = kb * 8 + kis;              // local ki in [0,256)
        const f32x4  a  = __builtin_nontemporal_load(tk4 + ki * 32 + c4);
        const float4 bk = kq4[ki * 32 + c4];
        float part = q4.x * (a.x + bk.x) + q4.y * (a.y + bk.y)
                   + q4.z * (a.z + bk.z) + q4.w * (a.w + bk.w);
        part += __shfl_xor(part, 1);
        part += __shfl_xor(part, 2);
        if ((c4 & 3) == 0)
            s_p[ki * SP_STRIDE + h] = part;
    }
    __syncthreads();

    // coalesced write-out: 8 floats per thread (un-padded)
    float buf[8];
    #pragma unroll
    for (int j = 0; j < 8; ++j) {
        const int idx = t * 8 + j;                // 0..2047
        buf[j] = s_p[(idx >> 3) * SP_STRIDE + (idx & 7)];
    }
    float4* dst = (float4*)(scores + (size_t)row * (LL * NH) + half * (LL / 2) * NH + t * 8);
    dst[0] = make_float4(buf[0], buf[1], buf[2], buf[3]);
    dst[1] = make_float4(buf[4], buf[5], buf[6], buf[7]);
}

// K_C: softmax (full row, duplicated per half) + partial ctx over one ki-half.
//   grid = BB*LL*2, 256 threads.
__global__ __launch_bounds__(256) void ctx_kernel(
    const float* __restrict__ scores,
    const float* __restrict__ vp,
    const float* __restrict__ time_v,
    const float* __restrict__ mask,
    float* __restrict__ pctx)
{
    const int half = blockIdx.x & 1;
    const int row  = blockIdx.x >> 1;
    const int b    = row >> 9;
    const int t    = threadIdx.x;
    const int c4   = t & 31;
    const int kis  = t >> 5;
    const int h    = c4 >> 2;

    __shared__ float s_p[LL * SP_STRIDE];   // full row [ki][h], 18.4 KB
    __shared__ float s_red[8][HH];
    __shared__ float s_inv[NH];

    // load full score row (4096 floats), scatter into padded LDS
    {
        const float4* src = (const float4*)(scores + (size_t)row * (LL * NH));
        #pragma unroll
        for (int j = 0; j < 4; ++j) {
            const float4 v4 = src[t * 4 + j];
            const int idx = t * 16 + j * 4;
            s_p[((idx + 0) >> 3) * SP_STRIDE + ((idx + 0) & 7)] = v4.x;
            s_p[((idx + 1) >> 3) * SP_STRIDE + ((idx + 1) & 7)] = v4.y;
            s_p[((idx + 2) >> 3) * SP_STRIDE + ((idx + 2) & 7)] = v4.z;
            s_p[((idx + 3) >> 3) * SP_STRIDE + ((idx + 3) & 7)] = v4.w;
        }
    }
    __syncthreads();

    // softmax per head row (32 threads per head); scale+mask here
    {
        const float* __restrict__ mrow = mask + (size_t)row * LL;
        const int hh  = t >> 5;
        const int l32 = t & 31;
        float v[LL / 32];
        float m = -1e30f;
        #pragma unroll
        for (int j = 0; j < LL / 32; ++j) {
            const int ki = l32 + j * 32;
            v[j] = s_p[ki * SP_STRIDE + hh] * 0.25f + mrow[ki];
            m = fmaxf(m, v[j]);
        }
        #pragma unroll
        for (int off = 16; off; off >>= 1) m = fmaxf(m, __shfl_xor(m, off));
        float sum = 0.f;
        #pragma unroll
        for (int j = 0; j < LL / 32; ++j) {
            const float e = __expf(v[j] - m);
            s_p[(l32 + j * 32) * SP_STRIDE + hh] = e;
            sum += e;
        }
        #pragma unroll
        for (int off = 16; off; off >>= 1) sum += __shfl_xor(sum, off);
        if (l32 == 0) s_inv[hh] = 1.0f / sum;
    }
    __syncthreads();

    // partial ctx over this half's ki range
    const f32x4*  __restrict__ tv4 = (const f32x4*)(time_v
        + (size_t)row * (size_t)(LL * HH) + (size_t)half * (LL / 2) * HH);
    const float4* __restrict__ vq4 = (const float4*)(vp
        + (size_t)b * (size_t)(LL * HH) + (size_t)half * (LL / 2) * HH);
    float4 acc = make_float4(0.f, 0.f, 0.f, 0.f);
    #pragma unroll 8
    for (int kb = 0; kb < LL / 2 / 8; ++kb) {
        const int ki = kb * 8 + kis;              // local ki
        const float p = s_p[(half * (LL / 2) + ki) * SP_STRIDE + h];
        const f32x4  a  = __builtin_nontemporal_load(tv4 + ki * 32 + c4);
        const float4 bv = vq4[ki * 32 + c4];
        acc.x = fmaf(p, a.x + bv.x, acc.x);
        acc.y = fmaf(p, a.y + bv.y, acc.y);
        acc.z = fmaf(p, a.z + bv.z, acc.z);
        acc.w = fmaf(p, a.w + bv.w, acc.w);
    }
    const float inv = s_inv[h];
    ((float4*)s_red)[kis * 32 + c4] = make_float4(acc.x * inv, acc.y * inv, acc.z * inv, acc.w * inv);
    __syncthreads();

    if (t < HH) {
        float cv = 0.f;
        #pragma unroll
        for (int r = 0; r < 8; ++r) cv += s_red[r][t];
        pctx[(size_t)half * (BB * LL * HH) + (size_t)row * HH + t] = cv;
    }
}

// K_D: ctx = pctx0+pctx1 ; out = ctx @ Wo + bo.  grid = BB*LL, 256 threads.
__global__ __launch_bounds__(256) void out_proj_kernel(
    const float* __restrict__ pctx,
    const float* __restrict__ Wo,
    const float* __restrict__ bo,
    float* __restrict__ out)
{
    const int row = blockIdx.x;
    const int t   = threadIdx.x;
    __shared__ float s_ctx[HH];
    __shared__ float s_red[2][HH];

    if (t < HH)
        s_ctx[t] = pctx[(size_t)row * HH + t]
                 + pctx[(size_t)(BB * LL * HH) + (size_t)row * HH + t];
    __syncthreads();

    {
        const int to   = t & (HH - 1);
        const int half = t >> 7;
        float o = half ? 0.f : bo[to];
        const int i0 = half * (HH / 2);
        #pragma unroll 4
        for (int i = i0; i < i0 + HH / 2; ++i)
            o = fmaf(s_ctx[i], Wo[i * HH + to], o);
        s_red[half][to] = o;
    }
    __syncthreads();
    if (t < HH)
        out[(size_t)row * HH + t] = s_red[0][t] + s_red[1][t];
}

// Fallback: fully fused attention (verified at 531 µs), used if ws too small.
__global__ __launch_bounds__(256) void attn_fused_kernel(
    const float* __restrict__ q,
    const float* __restrict__ kp,
    const float* __restrict__ vp,
    const float* __restrict__ time_k,
    const float* __restrict__ time_v,
    const float* __restrict__ mask,
    const float* __restrict__ Wo,
    const float* __restrict__ bo,
    float* __restrict__ out)
{
    const int blk = blockIdx.x;
    const int b   = blk >> 9;
    const int qi  = blk & (LL - 1);
    const int t   = threadIdx.x;
    const int c4  = t & 31;
    const int kis = t >> 5;
    const int h   = c4 >> 2;

    __shared__ float s_p[LL * SP_STRIDE];
    __shared__ float s_q[HH];
    __shared__ float s_red[8][HH];
    __shared__ float s_ctx[HH];
    __shared__ float s_inv[NH];

    if (t < HH) s_q[t] = q[(b * LL + qi) * HH + t];
    __syncthreads();

    const float4 q4 = ((const float4*)s_q)[c4];
    const f32x4* __restrict__ tk4 = (const f32x4*)(time_k + (size_t)(b * LL + qi) * (size_t)(LL * HH));
    const float4* __restrict__ kq4 = (const float4*)(kp + (size_t)b * (size_t)(LL * HH));
    const float*  __restrict__ mrow = mask + (size_t)(b * LL + qi) * LL;

    #pragma unroll 8
    for (int kb = 0; kb < LL / 8; ++kb) {
        const int ki = kb * 8 + kis;
        const f32x4  a  = __builtin_nontemporal_load(tk4 + ki * 32 + c4);
        const float4 bk = kq4[ki * 32 + c4];
        float part = q4.x * (a.x + bk.x) + q4.y * (a.y + bk.y)
                   + q4.z * (a.z + bk.z) + q4.w * (a.w + bk.w);
        part += __shfl_xor(part, 1);
        part += __shfl_xor(part, 2);
        if ((c4 & 3) == 0)
            s_p[ki * SP_STRIDE + h] = part;
    }
    __syncthreads();

    {
        const int hh  = t >> 5;
        const int l32 = t & 31;
        float v[LL / 32];
        float m = -1e30f;
        #pragma unroll
        for (int j = 0; j < LL / 32; ++j) {
            const int ki = l32 + j * 32;
            v[j] = s_p[ki * SP_STRIDE + hh] * 0.25f + mrow[ki];
            m = fmaxf(m, v[j]);
        }
        #pragma unroll
        for (int off = 16; off; off >>= 1) m = fmaxf(m, __shfl_xor(m, off));
        float sum = 0.f;
        #pragma unroll
        for (int j = 0; j < LL / 32; ++j) {
            const float e = __expf(v[j] - m);
            s_p[(l32 + j * 32) * SP_STRIDE + hh] = e;
            sum += e;
        }
        #pragma unroll
        for (int off = 16; off; off >>= 1) sum += __shfl_xor(sum, off);
        if (l32 == 0) s_inv[hh] = 1.0f / sum;
    }
    __syncthreads();

    const f32x4* __restrict__ tv4 = (const f32x4*)(time_v + (size_t)(b * LL + qi) * (size_t)(LL * HH));
    const float4* __restrict__ vq4 = (const float4*)(vp + (size_t)b * (size_t)(LL * HH));
    float4 acc = make_float4(0.f, 0.f, 0.f, 0.f);
    #pragma unroll 8
    for (int kb = 0; kb < LL / 8; ++kb) {
        const int ki = kb * 8 + kis;
        const float p = s_p[ki * SP_STRIDE + h];
        const f32x4  a  = __builtin_nontemporal_load(tv4 + ki * 32 + c4);
        const float4 bv = vq4[ki * 32 + c4];
        acc.x = fmaf(p, a.x + bv.x, acc.x);
        acc.y = fmaf(p, a.y + bv.y, acc.y);
        acc.z = fmaf(p, a.z + bv.z, acc.z);
        acc.w = fmaf(p, a.w + bv.w, acc.w);
    }
    const float inv = s_inv[h];
    ((float4*)s_red)[kis * 32 + c4] = make_float4(acc.x * inv, acc.y * inv, acc.z * inv, acc.w * inv);
    __syncthreads();

    if (t < HH) {
        float cv = 0.f;
        #pragma unroll
        for (int r = 0; r < 8; ++r) cv += s_red[r][t];
        s_ctx[t] = cv;
    }
    __syncthreads();

    {
        const int to   = t & (HH - 1);
        const int half = t >> 7;
        float o = half ? 0.f : bo[to];
        const int i0 = half * (HH / 2);
        #pragma unroll 4
        for (int i = i0; i < i0 + HH / 2; ++i)
            o = fmaf(s_ctx[i], Wo[i * HH + to], o);
        __syncthreads();
        s_red[half][to] = o;
    }
    __syncthreads();
    if (t < HH)
        out[(b * LL + qi) * HH + t] = s_red[0][t] + s_red[1][t];
}

extern "C" void kernel_launch(void* const* d_in, const int* in_sizes, int n_in,
                              void* d_out, int out_size, void* d_ws, size_t ws_size,
                              hipStream_t stream) {
    const float* x         = (const float*)d_in[0];
    const float* time_k    = (const float*)d_in[1];
    const float* time_v    = (const float*)d_in[2];
    const float* abs_pos_k = (const float*)d_in[3];
    const float* abs_pos_v = (const float*)d_in[4];
    const float* attn_mask = (const float*)d_in[5];
    const float* Wq = (const float*)d_in[6];
    const float* bq = (const float*)d_in[7];
    const float* Wk = (const float*)d_in[8];
    const float* bk = (const float*)d_in[9];
    const float* Wv = (const float*)d_in[10];
    const float* bv = (const float*)d_in[11];
    const float* Wo = (const float*)d_in[12];
    const float* bo = (const float*)d_in[13];
    float* out = (float*)d_out;

    float* q  = (float*)d_ws;              // [2*512*128]
    float* kp = q  + BB * LL * HH;         // k + abs_k
    float* vp = kp + BB * LL * HH;         // v + abs_v

    qkv_proj_kernel<<<BB * LL / 4, 128, 0, stream>>>(
        x, abs_pos_k, abs_pos_v, Wq, bq, Wk, bk, Wv, bv, q, kp, vp);

    // split path needs qkv (1.5 MB) + scores (16 MB) + pctx (1 MB)
    const size_t need = (size_t)(3 * BB * LL * HH            // q, kp, vp
                               + (size_t)BB * LL * LL * NH   // scores
                               + 2 * BB * LL * HH) * 4;      // pctx
    if (ws_size >= need) {
        float* scores = vp + BB * LL * HH;
        float* pctx   = scores + (size_t)BB * LL * LL * NH;
        score_kernel<<<BB * LL * 2, 256, 0, stream>>>(q, kp, time_k, scores);
        ctx_kernel<<<BB * LL * 2, 256, 0, stream>>>(scores, vp, time_v, attn_mask, pctx);
        out_proj_kernel<<<BB * LL, 256, 0, stream>>>(pctx, Wo, bo, out);
    } else {
        attn_fused_kernel<<<BB * LL, 256, 0, stream>>>(
            q, kp, vp, time_k, time_v, attn_mask, Wo, bo, out);
    }
}

// Round 4
// 530.677 us; speedup vs baseline: 1.0230x; 1.0230x over previous
//
#include <hip/hip_runtime.h>

#define BB 2
#define LL 512
#define HH 128
#define NH 8
#define SP_STRIDE 9   // pad 8 heads to 9 -> odd stride, conflict-free
#define KHALF 256     // ki rows per block (2-way flash split)

typedef float f32x4 __attribute__((ext_vector_type(4)));

// K1: q = x@Wq+bq ; kp = x@Wk+bk+abs_pos_k ; vp = x@Wv+bv+abs_pos_v
__global__ __launch_bounds__(128) void qkv_proj_kernel(
    const float* __restrict__ x,
    const float* __restrict__ abs_pos_k,
    const float* __restrict__ abs_pos_v,
    const float* __restrict__ Wq, const float* __restrict__ bq,
    const float* __restrict__ Wk, const float* __restrict__ bk,
    const float* __restrict__ Wv, const float* __restrict__ bv,
    float* __restrict__ q, float* __restrict__ kp, float* __restrict__ vp)
{
    const int r0 = blockIdx.x * 4;
    const int c = threadIdx.x;
    __shared__ float xs[4][HH];
    #pragma unroll
    for (int r = 0; r < 4; ++r) xs[r][c] = x[(r0 + r) * HH + c];
    __syncthreads();
    float aq[4], ak[4], av[4];
    #pragma unroll
    for (int r = 0; r < 4; ++r) { aq[r] = bq[c]; ak[r] = bk[c]; av[r] = bv[c]; }
    #pragma unroll 4
    for (int i = 0; i < HH; ++i) {
        const float wq = Wq[i * HH + c];
        const float wk = Wk[i * HH + c];
        const float wv = Wv[i * HH + c];
        #pragma unroll
        for (int r = 0; r < 4; ++r) {
            const float xv = xs[r][i];
            aq[r] = fmaf(xv, wq, aq[r]);
            ak[r] = fmaf(xv, wk, ak[r]);
            av[r] = fmaf(xv, wv, av[r]);
        }
    }
    #pragma unroll
    for (int r = 0; r < 4; ++r) {
        const int idx = (r0 + r) * HH + c;
        q[idx]  = aq[r];
        kp[idx] = ak[r] + abs_pos_k[idx];
        vp[idx] = av[r] + abs_pos_v[idx];
    }
}

// K2: flash-style half-row attention. grid = BB*LL*2 (8 blocks/CU -> 100% occ).
// Each block: (row, half). Local scores -> local softmax (m,s per head) ->
// UNNORMALIZED partial ctx. Combine kernel applies the flash correction.
//   t = kis*32 + c4 ; h = c4>>2.
__global__ __launch_bounds__(256) void attn_flash_kernel(
    const float* __restrict__ q,
    const float* __restrict__ kp,
    const float* __restrict__ vp,
    const float* __restrict__ time_k,
    const float* __restrict__ time_v,
    const float* __restrict__ mask,
    float* __restrict__ pctx,     // [2][BB*LL][HH] raw (unnormalized)
    float2* __restrict__ msbuf)   // [2][BB*LL][NH] {max, expsum}
{
    const int half = blockIdx.x & 1;
    const int row  = blockIdx.x >> 1;
    const int b    = row >> 9;
    const int t    = threadIdx.x;
    const int c4   = t & 31;
    const int kis  = t >> 5;
    const int h    = c4 >> 2;

    __shared__ float s_q[HH];
    __shared__ float s_p[KHALF * SP_STRIDE];  // 256 ki x 8 h, pad 9 (9.2 KB)
    __shared__ float s_red[8][HH];            // ctx partials (4 KB)

    if (t < HH) s_q[t] = q[row * HH + t];
    __syncthreads();

    const float4 q4 = ((const float4*)s_q)[c4];
    const f32x4*  __restrict__ tk4 = (const f32x4*)(time_k
        + (size_t)row * (size_t)(LL * HH) + (size_t)half * KHALF * HH);
    const float4* __restrict__ kq4 = (const float4*)(kp
        + (size_t)b * (size_t)(LL * HH) + (size_t)half * KHALF * HH);

    // ---- phase 1: raw scores for this half's ki range
    #pragma unroll 8
    for (int kb = 0; kb < KHALF / 8; ++kb) {
        const int ki = kb * 8 + kis;              // local ki in [0,256)
        const f32x4  a  = __builtin_nontemporal_load(tk4 + ki * 32 + c4);
        const float4 bk = kq4[ki * 32 + c4];
        float part = q4.x * (a.x + bk.x) + q4.y * (a.y + bk.y)
                   + q4.z * (a.z + bk.z) + q4.w * (a.w + bk.w);
        part += __shfl_xor(part, 1);
        part += __shfl_xor(part, 2);
        if ((c4 & 3) == 0)
            s_p[ki * SP_STRIDE + h] = part;
    }
    __syncthreads();

    // ---- phase 2: LOCAL softmax per head (32 threads/head); scale+mask here.
    // Stores exp(v - m_local) back to s_p; writes {m_local, sum_local} to msbuf.
    {
        const float* __restrict__ mrow = mask + (size_t)row * LL + half * KHALF;
        const int hh  = t >> 5;
        const int l32 = t & 31;
        float v[KHALF / 32];                      // 8
        float m = -1e30f;
        #pragma unroll
        for (int j = 0; j < KHALF / 32; ++j) {
            const int ki = l32 + j * 32;
            v[j] = s_p[ki * SP_STRIDE + hh] * 0.25f + mrow[ki];
            m = fmaxf(m, v[j]);
        }
        #pragma unroll
        for (int off = 16; off; off >>= 1) m = fmaxf(m, __shfl_xor(m, off));
        float sum = 0.f;
        #pragma unroll
        for (int j = 0; j < KHALF / 32; ++j) {
            const float e = __expf(v[j] - m);
            s_p[(l32 + j * 32) * SP_STRIDE + hh] = e;
            sum += e;
        }
        #pragma unroll
        for (int off = 16; off; off >>= 1) sum += __shfl_xor(sum, off);
        if (l32 == 0)
            msbuf[((size_t)half * (BB * LL) + row) * NH + hh] = make_float2(m, sum);
    }
    __syncthreads();

    // ---- phase 3: UNNORMALIZED partial ctx over this half's ki range
    const f32x4*  __restrict__ tv4 = (const f32x4*)(time_v
        + (size_t)row * (size_t)(LL * HH) + (size_t)half * KHALF * HH);
    const float4* __restrict__ vq4 = (const float4*)(vp
        + (size_t)b * (size_t)(LL * HH) + (size_t)half * KHALF * HH);
    float4 acc = make_float4(0.f, 0.f, 0.f, 0.f);
    #pragma unroll 8
    for (int kb = 0; kb < KHALF / 8; ++kb) {
        const int ki = kb * 8 + kis;              // local ki
        const float p = s_p[ki * SP_STRIDE + h];
        const f32x4  a  = __builtin_nontemporal_load(tv4 + ki * 32 + c4);
        const float4 bv = vq4[ki * 32 + c4];
        acc.x = fmaf(p, a.x + bv.x, acc.x);
        acc.y = fmaf(p, a.y + bv.y, acc.y);
        acc.z = fmaf(p, a.z + bv.z, acc.z);
        acc.w = fmaf(p, a.w + bv.w, acc.w);
    }
    ((float4*)s_red)[kis * 32 + c4] = acc;
    __syncthreads();

    if (t < HH) {
        float cv = 0.f;
        #pragma unroll
        for (int r = 0; r < 8; ++r) cv += s_red[r][t];
        pctx[(size_t)half * (BB * LL * HH) + (size_t)row * HH + t] = cv;
    }
}

// K3: flash combine of the two halves + out-projection. grid = BB*LL.
__global__ __launch_bounds__(256) void combine_kernel(
    const float* __restrict__ pctx,
    const float2* __restrict__ msbuf,
    const float* __restrict__ Wo,
    const float* __restrict__ bo,
    float* __restrict__ out)
{
    const int row = blockIdx.x;
    const int t   = threadIdx.x;
    __shared__ float s_ctx[HH];
    __shared__ float s_red[2][HH];

    if (t < HH) {
        const int h = t >> 4;                     // 16 dims per head
        const float2 ms0 = msbuf[(size_t)row * NH + h];
        const float2 ms1 = msbuf[(size_t)(BB * LL + row) * NH + h];
        const float M  = fmaxf(ms0.x, ms1.x);
        const float e0 = __expf(ms0.x - M);
        const float e1 = __expf(ms1.x - M);
        const float denom = ms0.y * e0 + ms1.y * e1;
        const float p0 = pctx[(size_t)row * HH + t];
        const float p1 = pctx[(size_t)(BB * LL * HH) + (size_t)row * HH + t];
        s_ctx[t] = (p0 * e0 + p1 * e1) / denom;
    }
    __syncthreads();

    {
        const int to   = t & (HH - 1);
        const int half = t >> 7;
        float o = half ? 0.f : bo[to];
        const int i0 = half * (HH / 2);
        #pragma unroll 4
        for (int i = i0; i < i0 + HH / 2; ++i)
            o = fmaf(s_ctx[i], Wo[i * HH + to], o);
        s_red[half][to] = o;
    }
    __syncthreads();
    if (t < HH)
        out[(size_t)row * HH + t] = s_red[0][t] + s_red[1][t];
}

extern "C" void kernel_launch(void* const* d_in, const int* in_sizes, int n_in,
                              void* d_out, int out_size, void* d_ws, size_t ws_size,
                              hipStream_t stream) {
    const float* x         = (const float*)d_in[0];
    const float* time_k    = (const float*)d_in[1];
    const float* time_v    = (const float*)d_in[2];
    const float* abs_pos_k = (const float*)d_in[3];
    const float* abs_pos_v = (const float*)d_in[4];
    const float* attn_mask = (const float*)d_in[5];
    const float* Wq = (const float*)d_in[6];
    const float* bq = (const float*)d_in[7];
    const float* Wk = (const float*)d_in[8];
    const float* bk = (const float*)d_in[9];
    const float* Wv = (const float*)d_in[10];
    const float* bv = (const float*)d_in[11];
    const float* Wo = (const float*)d_in[12];
    const float* bo = (const float*)d_in[13];
    float* out = (float*)d_out;

    float*  q     = (float*)d_ws;                        // [2*512*128]
    float*  kp    = q  + BB * LL * HH;                   // k + abs_k
    float*  vp    = kp + BB * LL * HH;                   // v + abs_v
    float*  pctx  = vp + BB * LL * HH;                   // [2][1024][128] = 1 MB
    float2* msbuf = (float2*)(pctx + 2 * BB * LL * HH);  // [2][1024][8] = 128 KB

    qkv_proj_kernel<<<BB * LL / 4, 128, 0, stream>>>(
        x, abs_pos_k, abs_pos_v, Wq, bq, Wk, bk, Wv, bv, q, kp, vp);

    attn_flash_kernel<<<BB * LL * 2, 256, 0, stream>>>(
        q, kp, vp, time_k, time_v, attn_mask, pctx, msbuf);

    combine_kernel<<<BB * LL, 256, 0, stream>>>(pctx, msbuf, Wo, bo, out);
}